// Round 1
// baseline (4713.473 us; speedup 1.0000x reference)
//
#include <hip/hip_runtime.h>
#include <hip/hip_bf16.h>
#include <math.h>

#define BATCH 128
#define SEQ   200
#define HID   1024
#define NH    4
#define DK    256
#define NF    101   // SEQ/2+1
#define LS    200   // LSESS
#define DB    16    // d-block width in spectral kernel

// ---------------------------------------------------------------------------
// DFT tables (ortho norm, N=200):
//  Fc[f*200+s] = cos(2*pi*f*s/200)/sqrt(200)
//  Fs[f*200+s] = sin(2*pi*f*s/200)/sqrt(200)
//  Gc[s*101+f] = a_f*cos(2*pi*f*s/200)/sqrt(200),  a_f = 1 for f in {0,100} else 2
//  Gs[s*101+f] = 2*sin(2*pi*f*s/200)/sqrt(200) for f in 1..99, else 0
// ---------------------------------------------------------------------------
__global__ void init_tables(float* __restrict__ Fc, float* __restrict__ Fs,
                            float* __restrict__ Gc, float* __restrict__ Gs) {
    int idx = blockIdx.x * 256 + threadIdx.x;
    const double inv = 0.07071067811865475244;  // 1/sqrt(200)
    const double PI2 = 6.283185307179586476925;
    if (idx < NF * SEQ) {
        int f = idx / SEQ, s = idx % SEQ;
        double ang = PI2 * (double)((f * s) % SEQ) / (double)SEQ;
        Fc[idx] = (float)(cos(ang) * inv);
        Fs[idx] = (float)(sin(ang) * inv);
    }
    if (idx < SEQ * NF) {
        int s = idx / NF, f = idx % NF;
        double ang = PI2 * (double)((f * s) % SEQ) / (double)SEQ;
        double al = (f == 0 || f == NF - 1) ? 1.0 : 2.0;
        Gc[idx] = (float)(al * cos(ang) * inv);
        Gs[idx] = (float)((f == 0 || f == NF - 1) ? 0.0 : 2.0 * sin(ang) * inv);
    }
}

// ---------------------------------------------------------------------------
// Generic 64x64-tile fp32 GEMM, 256 threads, BK=16, 4x4 microtile.
// C[m,n] = sum_k opA(A)[m,k] * opB(B)[k,n]   (+ optional epilogues)
// TRANS_A: A stored (K,M) row-major.  TRANS_B: B stored (N,K) row-major.
// RELU_BIAS_A: A element -> max(A + biasK[k], 0) on load.
// ADD_BIAS_N: C += biasN[n] on store.
// Batch: z -> (outer, inner) via nInner; per-operand (outer, inner) strides.
// ---------------------------------------------------------------------------
template <bool TRANS_A, bool TRANS_B, bool RELU_BIAS_A, bool ADD_BIAS_N>
__global__ void gemm64(const float* __restrict__ A, const float* __restrict__ B,
                       float* __restrict__ C, int M, int N, int K,
                       int lda, int ldb, int ldc,
                       long aOuter, long aInner, long bOuter, long bInner,
                       long cOuter, long cInner, int nInner,
                       const float* __restrict__ biasK,
                       const float* __restrict__ biasN) {
    int bz = blockIdx.z;
    int bo = bz / nInner, bi = bz % nInner;
    const float* Ab = A + bo * aOuter + bi * aInner;
    const float* Bb = B + bo * bOuter + bi * bInner;
    float* Cb = C + bo * cOuter + bi * cInner;

    __shared__ float As[16][65];
    __shared__ float Bs[16][65];

    int tid = threadIdx.x;
    int m0 = blockIdx.y * 64;
    int n0 = blockIdx.x * 64;
    int tx = tid % 16, ty = tid / 16;

    float acc[4][4] = {};

    for (int k0 = 0; k0 < K; k0 += 16) {
        // ---- load A tile -> As[k][m]
        if (!TRANS_A) {
            int k = tid % 16, mBase = tid / 16;
#pragma unroll
            for (int p = 0; p < 4; ++p) {
                int m = mBase + p * 16;
                int gm = m0 + m, gk = k0 + k;
                float v = 0.f;
                if (gm < M && gk < K) {
                    v = Ab[(long)gm * lda + gk];
                    if (RELU_BIAS_A) v = fmaxf(v + biasK[gk], 0.f);
                }
                As[k][m] = v;
            }
        } else {
            int m = tid % 64, kBase = tid / 64;
#pragma unroll
            for (int p = 0; p < 4; ++p) {
                int k = kBase + p * 4;
                int gm = m0 + m, gk = k0 + k;
                float v = 0.f;
                if (gm < M && gk < K) v = Ab[(long)gk * lda + gm];
                As[k][m] = v;
            }
        }
        // ---- load B tile -> Bs[k][n]
        if (!TRANS_B) {
            int n = tid % 64, kBase = tid / 64;
#pragma unroll
            for (int p = 0; p < 4; ++p) {
                int k = kBase + p * 4;
                int gn = n0 + n, gk = k0 + k;
                float v = 0.f;
                if (gk < K && gn < N) v = Bb[(long)gk * ldb + gn];
                Bs[k][n] = v;
            }
        } else {
            int k = tid % 16, nBase = tid / 16;
#pragma unroll
            for (int p = 0; p < 4; ++p) {
                int n = nBase + p * 16;
                int gn = n0 + n, gk = k0 + k;
                float v = 0.f;
                if (gn < N && gk < K) v = Bb[(long)gn * ldb + gk];
                Bs[k][n] = v;
            }
        }
        __syncthreads();
#pragma unroll
        for (int kk = 0; kk < 16; ++kk) {
            float a[4], b[4];
#pragma unroll
            for (int i = 0; i < 4; ++i) a[i] = As[kk][ty * 4 + i];
#pragma unroll
            for (int j = 0; j < 4; ++j) b[j] = Bs[kk][tx * 4 + j];
#pragma unroll
            for (int i = 0; i < 4; ++i)
#pragma unroll
                for (int j = 0; j < 4; ++j)
                    acc[i][j] = fmaf(a[i], b[j], acc[i][j]);
        }
        __syncthreads();
    }
#pragma unroll
    for (int i = 0; i < 4; ++i) {
        int gm = m0 + ty * 4 + i;
        if (gm >= M) continue;
#pragma unroll
        for (int j = 0; j < 4; ++j) {
            int gn = n0 + tx * 4 + j;
            if (gn >= N) continue;
            float v = acc[i][j];
            if (ADD_BIAS_N) v += biasN[gn];
            Cb[(long)gm * ldc + gn] = v;
        }
    }
}

// ---------------------------------------------------------------------------
// Fused spectral kernel: per (b,h, 16-wide d-block)
//   corr = irfft( rfft(Qp) * conj(rfft(Kp)) * weight )  along s, ortho norm.
// Stages the Qp/Kp slice in LDS, writes corr back over Qp in place.
// ---------------------------------------------------------------------------
__global__ void spectral_kernel(float* __restrict__ Qp, const float* __restrict__ Kp,
                                const float* __restrict__ cw,
                                const float* __restrict__ Fc, const float* __restrict__ Fs,
                                const float* __restrict__ Gc, const float* __restrict__ Gs) {
    int blk = blockIdx.x;              // B*NH*(DK/DB) = 8192
    int db = blk % (DK / DB);
    int bh = blk / (DK / DB);
    int h = bh % NH;
    long base = (long)bh * SEQ * DK + db * DB;

    __shared__ float Qs[SEQ][DB];
    __shared__ float Ks[SEQ][DB];
    __shared__ float Rr[NF][DB];
    __shared__ float Ri[NF][DB];

    int tid = threadIdx.x;  // 256
    for (int idx = tid; idx < SEQ * DB; idx += 256) {
        int s = idx / DB, d = idx % DB;
        Qs[s][d] = Qp[base + (long)s * DK + d];
        Ks[s][d] = Kp[base + (long)s * DK + d];
    }
    __syncthreads();

    // forward DFT for q and k + pointwise product with weight
    for (int idx = tid; idx < NF * DB; idx += 256) {
        int f = idx / DB, d = idx % DB;
        float qr = 0.f, qi = 0.f, kr = 0.f, ki = 0.f;
        const float* fc = Fc + f * SEQ;
        const float* fs = Fs + f * SEQ;
        for (int s = 0; s < SEQ; ++s) {
            float c = fc[s], sn = fs[s];
            float qv = Qs[s][d], kv = Ks[s][d];
            qr = fmaf(c, qv, qr);
            qi = fmaf(-sn, qv, qi);
            kr = fmaf(c, kv, kr);
            ki = fmaf(-sn, kv, ki);
        }
        // cross = qf * conj(kf)
        float cr = qr * kr + qi * ki;
        float ci = qi * kr - qr * ki;
        long wi_idx = (((long)h * NF + f) * DK + (db * DB + d)) * 2;
        float wr = cw[wi_idx], wim = cw[wi_idx + 1];
        Rr[f][d] = cr * wr - ci * wim;
        Ri[f][d] = cr * wim + ci * wr;
    }
    __syncthreads();

    // inverse DFT -> corr, overwrite Qp slice in place
    for (int idx = tid; idx < SEQ * DB; idx += 256) {
        int s = idx / DB, d = idx % DB;
        float acc = 0.f;
        const float* gc = Gc + s * NF;
        const float* gs = Gs + s * NF;
        for (int f = 0; f < NF; ++f) {
            acc = fmaf(gc[f], Rr[f][d], acc);
            acc = fmaf(-gs[f], Ri[f][d], acc);
        }
        Qp[base + (long)s * DK + d] = acc;
    }
}

// ---------------------------------------------------------------------------
// Softmax over the s axis of alpha (B*NH, SEQ, LS): one block per (b,h).
// ---------------------------------------------------------------------------
__global__ void softmax_s_kernel(float* __restrict__ alpha) {
    int bh = blockIdx.x;
    int l = threadIdx.x;
    if (l >= LS) return;
    float* p = alpha + (long)bh * SEQ * LS;
    float m = -1e30f;
    for (int s = 0; s < SEQ; ++s) m = fmaxf(m, p[(long)s * LS + l]);
    float sum = 0.f;
    for (int s = 0; s < SEQ; ++s) sum += expf(p[(long)s * LS + l] - m);
    float inv = 1.f / sum;
    for (int s = 0; s < SEQ; ++s) {
        long i = (long)s * LS + l;
        p[i] = expf(p[i] - m) * inv;
    }
}

// ---------------------------------------------------------------------------
// gelu(erf) + TF LayerNorm (eps inside sqrt) per 1024-wide row.
// ---------------------------------------------------------------------------
__global__ void gelu_ln_kernel(const float* __restrict__ y2,
                               const float* __restrict__ lnw, const float* __restrict__ lnb,
                               float* __restrict__ out) {
    long r = blockIdx.x;
    const float4* xr = reinterpret_cast<const float4*>(y2 + r * HID);
    int tid = threadIdx.x;  // 256
    float4 v4 = xr[tid];
    float g[4];
    g[0] = 0.5f * v4.x * (1.f + erff(v4.x * 0.70710678118654752f));
    g[1] = 0.5f * v4.y * (1.f + erff(v4.y * 0.70710678118654752f));
    g[2] = 0.5f * v4.z * (1.f + erff(v4.z * 0.70710678118654752f));
    g[3] = 0.5f * v4.w * (1.f + erff(v4.w * 0.70710678118654752f));

    __shared__ float red[4];
    float s = g[0] + g[1] + g[2] + g[3];
#pragma unroll
    for (int o = 32; o > 0; o >>= 1) s += __shfl_down(s, o);
    if ((tid & 63) == 0) red[tid >> 6] = s;
    __syncthreads();
    float mean = (red[0] + red[1] + red[2] + red[3]) * (1.f / (float)HID);

    float v2 = 0.f;
#pragma unroll
    for (int p = 0; p < 4; ++p) {
        float d = g[p] - mean;
        v2 += d * d;
    }
    __syncthreads();
#pragma unroll
    for (int o = 32; o > 0; o >>= 1) v2 += __shfl_down(v2, o);
    if ((tid & 63) == 0) red[tid >> 6] = v2;
    __syncthreads();
    float var = (red[0] + red[1] + red[2] + red[3]) * (1.f / (float)HID);
    float rstd = rsqrtf(var + 1e-12f);

    float4 o4;
    int i0 = tid * 4;
    o4.x = (g[0] - mean) * rstd * lnw[i0 + 0] + lnb[i0 + 0];
    o4.y = (g[1] - mean) * rstd * lnw[i0 + 1] + lnb[i0 + 1];
    o4.z = (g[2] - mean) * rstd * lnw[i0 + 2] + lnb[i0 + 2];
    o4.w = (g[3] - mean) * rstd * lnw[i0 + 3] + lnb[i0 + 3];
    reinterpret_cast<float4*>(out + r * HID)[tid] = o4;
}

// ---------------------------------------------------------------------------
extern "C" void kernel_launch(void* const* d_in, const int* in_sizes, int n_in,
                              void* d_out, int out_size, void* d_ws, size_t ws_size,
                              hipStream_t stream) {
    const float* query = (const float*)d_in[0];
    const float* key = (const float*)d_in[1];
    const float* value = (const float*)d_in[2];
    const float* w0 = (const float*)d_in[3];
    const float* w1 = (const float*)d_in[4];
    const float* w2 = (const float*)d_in[5];
    const float* w3 = (const float*)d_in[6];
    const float* attn_bias = (const float*)d_in[7];
    const float* cw = (const float*)d_in[8];
    const float* lw = (const float*)d_in[9];
    const float* lb = (const float*)d_in[10];
    const float* lnw = (const float*)d_in[11];
    const float* lnb = (const float*)d_in[12];
    float* out = (float*)d_out;

    float* ws = (float*)d_ws;
    float* Fc = ws;                 // 20200
    float* Fs = Fc + 20200;
    float* Gc = Fs + 20200;
    float* Gs = Gc + 20200;         // ends 80800
    float* Qp = ws + 81920;         // 26,214,400  (B,H,S,DK); becomes corr, then y2
    float* Kp = Qp + 26214400;      // 26,214,400  (B,H,S,DK); becomes x (B,L,HID)
    float* Vp = Kp + 26214400;      // 26,214,400
    float* alpha = Vp + 26214400;   // 20,480,000  (B,H,S,L)
    float* xb = Kp;                 // reuse
    float* y2 = Qp;                 // reuse

    const long BH = (long)BATCH * NH;

    init_tables<<<79, 256, 0, stream>>>(Fc, Fs, Gc, Gs);

    // head-split projections: (200x256) @ (256x256), batched over 512 (b,h)
    dim3 gproj(4, 4, BH);
    gemm64<false, false, false, false><<<gproj, 256, 0, stream>>>(
        query, w0, Qp, SEQ, DK, DK, HID, DK, DK,
        (long)SEQ * HID, (long)DK, 0L, 0L,
        (long)NH * SEQ * DK, (long)SEQ * DK, NH, nullptr, nullptr);
    gemm64<false, false, false, false><<<gproj, 256, 0, stream>>>(
        key, w1, Kp, SEQ, DK, DK, HID, DK, DK,
        (long)SEQ * HID, (long)DK, 0L, 0L,
        (long)NH * SEQ * DK, (long)SEQ * DK, NH, nullptr, nullptr);
    gemm64<false, false, false, false><<<gproj, 256, 0, stream>>>(
        value, w2, Vp, SEQ, DK, DK, HID, DK, DK,
        (long)SEQ * HID, (long)DK, 0L, 0L,
        (long)NH * SEQ * DK, (long)SEQ * DK, NH, nullptr, nullptr);

    // spectral: DFT -> cross-spectrum * weight -> iDFT (corr overwrites Qp)
    spectral_kernel<<<BH * (DK / DB), 256, 0, stream>>>(Qp, Kp, cw, Fc, Fs, Gc, Gs);

    // alpha = relu(corr + bias) @ w3^T : (200x256)@(256x200), NT
    dim3 galpha(4, 4, BH);
    gemm64<false, true, true, false><<<galpha, 256, 0, stream>>>(
        Qp, w3, alpha, SEQ, LS, DK, DK, DK, LS,
        (long)NH * SEQ * DK, (long)SEQ * DK, 0L, 0L,
        (long)NH * SEQ * LS, (long)SEQ * LS, NH, attn_bias, nullptr);

    // softmax over s
    softmax_s_kernel<<<BH, 256, 0, stream>>>(alpha);

    // x[b,l,h*DK+d] = sum_s alpha[b,h,s,l] * Vp[b,h,s,d] : TN GEMM
    dim3 gx(4, 4, BH);
    gemm64<true, false, false, false><<<gx, 256, 0, stream>>>(
        alpha, Vp, xb, LS, DK, SEQ, LS, DK, HID,
        (long)NH * SEQ * LS, (long)SEQ * LS,
        (long)NH * SEQ * DK, (long)SEQ * DK,
        (long)LS * HID, (long)DK, NH, nullptr, nullptr);

    // y2 = x @ linear_w^T + linear_b : (25600x1024)@(1024x1024), NT
    dim3 glin(HID / 64, (BATCH * LS) / 64, 1);
    gemm64<false, true, false, true><<<glin, 256, 0, stream>>>(
        xb, lw, y2, BATCH * LS, HID, HID, HID, HID, HID,
        0L, 0L, 0L, 0L, 0L, 0L, 1, nullptr, lb);

    // gelu + LayerNorm
    gelu_ln_kernel<<<(long)BATCH * LS, 256, 0, stream>>>(y2, lnw, lnb, out);
}

// Round 2
// 961.493 us; speedup vs baseline: 4.9022x; 4.9022x over previous
//
#include <hip/hip_runtime.h>
#include <hip/hip_bf16.h>
#include <math.h>

#define BATCH 128
#define SEQ   200
#define HID   1024
#define NH    4
#define DK    256
#define NF    101    // SEQ/2+1
#define NF2   202    // stacked real+imag rows
#define NFP   208    // padded fidx dim (16B-aligned bf16 rows)
#define LS    200

typedef __attribute__((ext_vector_type(8))) short bf16x8;
typedef __attribute__((ext_vector_type(4))) float f32x4;

__device__ __forceinline__ unsigned short f2bf(float f) {
    union { float f; unsigned u; } v; v.f = f;
    unsigned r = v.u + 0x7fff + ((v.u >> 16) & 1);
    return (unsigned short)(r >> 16);
}
__device__ __forceinline__ float bf2f(unsigned short h) {
    union { unsigned u; float f; } v; v.u = ((unsigned)h) << 16;
    return v.f;
}

// ---------------------------------------------------------------------------
// DFT tables, bf16.
// F_stack (202 x 200): row f<101: cos(2pi f s/200)/sqrt(200); row 101+f: -sin(...)/sqrt(200)
// G_stack (200 x 208): col j<101: a_j cos(2pi j s/200)/sqrt(200), a_j=1 for j in {0,100} else 2
//                      col 101+f: f in {0,100} ? 0 : -2 sin(2pi f s/200)/sqrt(200); cols >=202: 0
// ---------------------------------------------------------------------------
__global__ void init_tables_bf16(unsigned short* __restrict__ F, unsigned short* __restrict__ G) {
    int idx = blockIdx.x * 256 + threadIdx.x;
    const double inv = 0.07071067811865475244;
    const double PI2 = 6.283185307179586476925;
    if (idx < NF2 * SEQ) {
        int fidx = idx / SEQ, s = idx % SEQ;
        int f = (fidx < NF) ? fidx : fidx - NF;
        double ang = PI2 * (double)((f * s) % SEQ) / (double)SEQ;
        double v = (fidx < NF) ? cos(ang) * inv : -sin(ang) * inv;
        F[idx] = f2bf((float)v);
    }
    if (idx < SEQ * NFP) {
        int s = idx / NFP, j = idx % NFP;
        double v = 0.0;
        if (j < NF) {
            double al = (j == 0 || j == NF - 1) ? 1.0 : 2.0;
            v = al * cos(PI2 * (double)((j * s) % SEQ) / (double)SEQ) * inv;
        } else if (j < NF2) {
            int f = j - NF;
            if (f != 0 && f != NF - 1)
                v = -2.0 * sin(PI2 * (double)((f * s) % SEQ) / (double)SEQ) * inv;
        }
        G[idx] = f2bf((float)v);
    }
}

// transpose-convert a 256x256 fp32 weight -> bf16 (dst[dout][din] = src[din][dout])
__global__ void wtrans256(const float* __restrict__ src, unsigned short* __restrict__ dst) {
    int dout = blockIdx.x, din = threadIdx.x;
    dst[dout * 256 + din] = f2bf(src[din * 256 + dout]);
}

__global__ void fconv(const float* __restrict__ src, unsigned short* __restrict__ dst, int n) {
    int i = blockIdx.x * 256 + threadIdx.x;
    if (i < n) dst[i] = f2bf(src[i]);
}

// ---------------------------------------------------------------------------
// bf16 MFMA GEMM, 64x64 block tile, 4 waves (each 32x32 = 2x2 frags), BK=32.
// LDS: As[64][BKP], Bs[64][BKP] -- both (row, k) with k contiguous.
// A source: bf16 (M,K) row-major. B source: bf16 (or fp32 if B_F32) (N,K) row-major.
// Fragment convention (m89/m92-verified family):
//   A frag: row = lane&15, k = (lane>>4)*8 + j   (contiguous bf16x8 from LDS)
//   C/D:    col = lane&15, row = (lane>>4)*4 + reg
// EPI: 0 = bf16 store; 1 = f32 store; 2 = relu(acc+biasN[n]) -> bf16; 3 = acc+biasN[n] -> f32
// ---------------------------------------------------------------------------
#define BKQ 32
#define BKP 40

template <bool B_F32, int EPI>
__global__ __launch_bounds__(256)
void mgemm(const void* __restrict__ Av, const void* __restrict__ Bv, void* __restrict__ Cv,
           int M, int N, int K, int lda, int ldb, int ldc,
           long aOuter, long aInner, long bOuter, long bInner,
           long cOuter, long cInner, int nInner,
           const float* __restrict__ biasN) {
    int bz = blockIdx.z;
    int bo = bz / nInner, bi = bz - bo * nInner;
    const unsigned short* A = (const unsigned short*)Av + bo * aOuter + bi * aInner;
    const unsigned short* Bh = nullptr;
    const float* Bf = nullptr;
    if (B_F32) Bf = (const float*)Bv + bo * bOuter + bi * bInner;
    else       Bh = (const unsigned short*)Bv + bo * bOuter + bi * bInner;

    __shared__ unsigned short As[64][BKP];
    __shared__ unsigned short Bs[64][BKP];

    int tid = threadIdx.x;
    int m0 = blockIdx.y * 64, n0 = blockIdx.x * 64;
    int lane = tid & 63, wave = tid >> 6;
    int wr = wave >> 1, wc = wave & 1;

    f32x4 acc[2][2] = {};

    int r = tid >> 2;
    int seg = (tid & 3) * 8;

    for (int k0 = 0; k0 < K; k0 += BKQ) {
        int kb = k0 + seg;
        // ---- stage A row (m0+r)
        {
            int gm = m0 + r;
            if (gm < M) {
                if (kb + 7 < K) {
                    *(bf16x8*)&As[r][seg] = *(const bf16x8*)(A + (long)gm * lda + kb);
                } else {
                    for (int j = 0; j < 8; ++j)
                        As[r][seg + j] = (kb + j < K) ? A[(long)gm * lda + kb + j] : (unsigned short)0;
                }
            } else {
                bf16x8 z = {0, 0, 0, 0, 0, 0, 0, 0};
                *(bf16x8*)&As[r][seg] = z;
            }
        }
        // ---- stage B row (n0+r)
        {
            int gn = n0 + r;
            if (gn < N) {
                if (!B_F32) {
                    if (kb + 7 < K) {
                        *(bf16x8*)&Bs[r][seg] = *(const bf16x8*)(Bh + (long)gn * ldb + kb);
                    } else {
                        for (int j = 0; j < 8; ++j)
                            Bs[r][seg + j] = (kb + j < K) ? Bh[(long)gn * ldb + kb + j] : (unsigned short)0;
                    }
                } else {
                    if (kb + 7 < K) {
                        const float4* p = reinterpret_cast<const float4*>(Bf + (long)gn * ldb + kb);
                        float4 x0 = p[0], x1 = p[1];
                        unsigned short t[8];
                        t[0] = f2bf(x0.x); t[1] = f2bf(x0.y); t[2] = f2bf(x0.z); t[3] = f2bf(x0.w);
                        t[4] = f2bf(x1.x); t[5] = f2bf(x1.y); t[6] = f2bf(x1.z); t[7] = f2bf(x1.w);
                        *(bf16x8*)&Bs[r][seg] = *(bf16x8*)t;
                    } else {
                        for (int j = 0; j < 8; ++j)
                            Bs[r][seg + j] = (kb + j < K) ? f2bf(Bf[(long)gn * ldb + kb + j]) : (unsigned short)0;
                    }
                }
            } else {
                bf16x8 z = {0, 0, 0, 0, 0, 0, 0, 0};
                *(bf16x8*)&Bs[r][seg] = z;
            }
        }
        __syncthreads();

        int la = lane & 15, kg = (lane >> 4) * 8;
        bf16x8 a0 = *(const bf16x8*)&As[wr * 32 + la][kg];
        bf16x8 a1 = *(const bf16x8*)&As[wr * 32 + 16 + la][kg];
        bf16x8 b0 = *(const bf16x8*)&Bs[wc * 32 + la][kg];
        bf16x8 b1 = *(const bf16x8*)&Bs[wc * 32 + 16 + la][kg];
        acc[0][0] = __builtin_amdgcn_mfma_f32_16x16x32_bf16(a0, b0, acc[0][0], 0, 0, 0);
        acc[0][1] = __builtin_amdgcn_mfma_f32_16x16x32_bf16(a0, b1, acc[0][1], 0, 0, 0);
        acc[1][0] = __builtin_amdgcn_mfma_f32_16x16x32_bf16(a1, b0, acc[1][0], 0, 0, 0);
        acc[1][1] = __builtin_amdgcn_mfma_f32_16x16x32_bf16(a1, b1, acc[1][1], 0, 0, 0);
        __syncthreads();
    }

    unsigned short* Ch = nullptr; float* Cf = nullptr;
    if (EPI == 1 || EPI == 3) Cf = (float*)Cv + bo * cOuter + bi * cInner;
    else                      Ch = (unsigned short*)Cv + bo * cOuter + bi * cInner;

#pragma unroll
    for (int mi = 0; mi < 2; ++mi) {
#pragma unroll
        for (int ni = 0; ni < 2; ++ni) {
            int gn = n0 + wc * 32 + ni * 16 + (lane & 15);
            if (gn >= N) continue;
            int gmBase = m0 + wr * 32 + mi * 16 + ((lane >> 4) << 2);
            float bN = 0.f;
            if (EPI == 2 || EPI == 3) bN = biasN[gn];
#pragma unroll
            for (int rr = 0; rr < 4; ++rr) {
                int gm = gmBase + rr;
                if (gm >= M) continue;
                float v = acc[mi][ni][rr];
                if (EPI == 0) Ch[(long)gm * ldc + gn] = f2bf(v);
                else if (EPI == 1) Cf[(long)gm * ldc + gn] = v;
                else if (EPI == 2) Ch[(long)gm * ldc + gn] = f2bf(fmaxf(v + bN, 0.f));
                else Cf[(long)gm * ldc + gn] = v + bN;
            }
        }
    }
}

// ---------------------------------------------------------------------------
// cross-spectrum * complex weight: R = qf * conj(kf) * w, per (bh, d, f).
// QF/KF/R layout: (bh, d, 208) bf16, [d][f]=real f, [d][101+f]=imag f.
// ---------------------------------------------------------------------------
__global__ void crossspec(const unsigned short* __restrict__ QF, const unsigned short* __restrict__ KF,
                          const float* __restrict__ cw, unsigned short* __restrict__ R) {
    long idx = (long)blockIdx.x * 256 + threadIdx.x;
    if (idx >= (long)BATCH * NH * DK * NF) return;
    int f = (int)(idx % NF);
    long t = idx / NF;
    int d = (int)(t % DK);
    int bh = (int)(t / DK);
    int h = bh & (NH - 1);
    long base = (long)bh * DK * NFP + (long)d * NFP;
    float qr = bf2f(QF[base + f]), qi = bf2f(QF[base + NF + f]);
    float kr = bf2f(KF[base + f]), ki = bf2f(KF[base + NF + f]);
    float cr = qr * kr + qi * ki;
    float ci = qi * kr - qr * ki;
    long wb = (((long)h * NF + f) * DK + d) * 2;
    float wr = cw[wb], wi = cw[wb + 1];
    R[base + f]      = f2bf(cr * wr - ci * wi);
    R[base + NF + f] = f2bf(cr * wi + ci * wr);
    if (f < NFP - NF2) R[base + NF2 + f] = 0;   // zero pad cols 202..207
}

// ---------------------------------------------------------------------------
// softmax over contiguous s (length 200) rows of alphaT (bh*200 rows), fp32 in -> bf16 out
// ---------------------------------------------------------------------------
__global__ __launch_bounds__(256) void softmax_rows(const float* __restrict__ in,
                                                    unsigned short* __restrict__ out) {
    long row = (long)blockIdx.x * 4 + (threadIdx.x >> 6);
    int lane = threadIdx.x & 63;
    const float* p = in + row * SEQ;
    float v[4];
    float m = -1e30f;
#pragma unroll
    for (int i = 0; i < 4; ++i) {
        int s = lane + 64 * i;
        v[i] = (s < SEQ) ? p[s] : -1e30f;
        m = fmaxf(m, v[i]);
    }
#pragma unroll
    for (int o = 32; o; o >>= 1) m = fmaxf(m, __shfl_xor(m, o));
    float e[4], sum = 0.f;
#pragma unroll
    for (int i = 0; i < 4; ++i) {
        int s = lane + 64 * i;
        e[i] = (s < SEQ) ? expf(v[i] - m) : 0.f;
        sum += e[i];
    }
#pragma unroll
    for (int o = 32; o; o >>= 1) sum += __shfl_xor(sum, o);
    float inv = 1.f / sum;
    unsigned short* q = out + row * SEQ;
#pragma unroll
    for (int i = 0; i < 4; ++i) {
        int s = lane + 64 * i;
        if (s < SEQ) q[s] = f2bf(e[i] * inv);
    }
}

// ---------------------------------------------------------------------------
// xT (bh, 256 d, 200 l) bf16  ->  X (b, l, h*256+d) bf16, 64x64 LDS-bounce tiles
// ---------------------------------------------------------------------------
__global__ __launch_bounds__(256) void transposeX(const unsigned short* __restrict__ xT,
                                                  unsigned short* __restrict__ X) {
    __shared__ unsigned short T[64][72];
    int bh = blockIdx.z, d0 = blockIdx.y * 64, l0 = blockIdx.x * 64;
    int b = bh >> 2, h = bh & 3;
    int tid = threadIdx.x;
    int r = tid >> 2, seg = (tid & 3) * 16;
    const unsigned short* src = xT + (long)bh * DK * LS + (long)(d0 + r) * LS + l0 + seg;
#pragma unroll
    for (int j = 0; j < 16; ++j) {
        int l = l0 + seg + j;
        T[r][seg + j] = (l < LS) ? src[j] : (unsigned short)0;
    }
    __syncthreads();
    int l = l0 + r;
    if (l < LS) {
        unsigned short* dst = X + ((long)b * LS + l) * HID + h * DK + d0 + seg;
#pragma unroll
        for (int j = 0; j < 16; ++j) dst[j] = T[seg + j][r];
    }
}

// ---------------------------------------------------------------------------
// gelu(erf) + TF LayerNorm per 1024-wide row (fp32 in, fp32 out)
// ---------------------------------------------------------------------------
__global__ __launch_bounds__(256) void gelu_ln_kernel(const float* __restrict__ y2,
                               const float* __restrict__ lnw, const float* __restrict__ lnb,
                               float* __restrict__ out) {
    long row = blockIdx.x;
    const float4* xr = reinterpret_cast<const float4*>(y2 + row * HID);
    int tid = threadIdx.x;
    float4 v4 = xr[tid];
    float g[4];
    g[0] = 0.5f * v4.x * (1.f + erff(v4.x * 0.70710678118654752f));
    g[1] = 0.5f * v4.y * (1.f + erff(v4.y * 0.70710678118654752f));
    g[2] = 0.5f * v4.z * (1.f + erff(v4.z * 0.70710678118654752f));
    g[3] = 0.5f * v4.w * (1.f + erff(v4.w * 0.70710678118654752f));

    __shared__ float red[4];
    float s = g[0] + g[1] + g[2] + g[3];
#pragma unroll
    for (int o = 32; o > 0; o >>= 1) s += __shfl_down(s, o);
    if ((tid & 63) == 0) red[tid >> 6] = s;
    __syncthreads();
    float mean = (red[0] + red[1] + red[2] + red[3]) * (1.f / (float)HID);

    float v2 = 0.f;
#pragma unroll
    for (int p = 0; p < 4; ++p) { float d = g[p] - mean; v2 += d * d; }
    __syncthreads();
#pragma unroll
    for (int o = 32; o > 0; o >>= 1) v2 += __shfl_down(v2, o);
    if ((tid & 63) == 0) red[tid >> 6] = v2;
    __syncthreads();
    float var = (red[0] + red[1] + red[2] + red[3]) * (1.f / (float)HID);
    float rstd = rsqrtf(var + 1e-12f);

    float4 o4;
    int i0 = tid * 4;
    o4.x = (g[0] - mean) * rstd * lnw[i0 + 0] + lnb[i0 + 0];
    o4.y = (g[1] - mean) * rstd * lnw[i0 + 1] + lnb[i0 + 1];
    o4.z = (g[2] - mean) * rstd * lnw[i0 + 2] + lnb[i0 + 2];
    o4.w = (g[3] - mean) * rstd * lnw[i0 + 3] + lnb[i0 + 3];
    reinterpret_cast<float4*>(out + row * HID)[tid] = o4;
}

// ---------------------------------------------------------------------------
extern "C" void kernel_launch(void* const* d_in, const int* in_sizes, int n_in,
                              void* d_out, int out_size, void* d_ws, size_t ws_size,
                              hipStream_t stream) {
    const float* query = (const float*)d_in[0];
    const float* key   = (const float*)d_in[1];
    const float* value = (const float*)d_in[2];
    const float* w0 = (const float*)d_in[3];
    const float* w1 = (const float*)d_in[4];
    const float* w2 = (const float*)d_in[5];
    const float* w3 = (const float*)d_in[6];
    const float* attn_bias = (const float*)d_in[7];
    const float* cw = (const float*)d_in[8];
    const float* lw = (const float*)d_in[9];
    const float* lb = (const float*)d_in[10];
    const float* lnw = (const float*)d_in[11];
    const float* lnb = (const float*)d_in[12];
    float* out = (float*)d_out;

    char* base = (char*)d_ws;
    auto AL = [](size_t x) { return (x + 511) & ~(size_t)511; };
    const long BH = (long)BATCH * NH;
    const size_t szPT = (size_t)BH * DK * SEQ * 2;   // 52,428,800 (bf16 (d,s) per bh)
    const size_t szSP = (size_t)BH * DK * NFP * 2;   // 54,525,952 (bf16 (d,208) per bh)

    size_t o = 0;
    size_t oF  = o; o = AL(o + (size_t)NF2 * SEQ * 2);
    size_t oG  = o; o = AL(o + (size_t)SEQ * NFP * 2);
    size_t oW0 = o; o = AL(o + 65536 * 2);
    size_t oW1 = o; o = AL(o + 65536 * 2);
    size_t oW2 = o; o = AL(o + 65536 * 2);
    size_t oW3 = o; o = AL(o + (size_t)LS * DK * 2);
    size_t oLW = o; o = AL(o + (size_t)HID * HID * 2);
    size_t oQ  = o; o = AL(o + szPT);   // qpT; later corr; later xT
    size_t oK  = o; o = AL(o + szPT);   // kpT; later X
    size_t oV  = o; o = AL(o + szPT);   // vpT; later y2 (spills into QF region)
    size_t oQF = o; o = AL(o + szSP);   // QF; later alphaT (spills into KF region)
    size_t oKF = o; o = AL(o + szSP);   // KF
    size_t oR  = o; o = AL(o + szSP);   // Rstack; later probs

    unsigned short* F_stack = (unsigned short*)(base + oF);
    unsigned short* G_stack = (unsigned short*)(base + oG);
    unsigned short* w0T = (unsigned short*)(base + oW0);
    unsigned short* w1T = (unsigned short*)(base + oW1);
    unsigned short* w2T = (unsigned short*)(base + oW2);
    unsigned short* w3b = (unsigned short*)(base + oW3);
    unsigned short* lwb = (unsigned short*)(base + oLW);
    unsigned short* qpT = (unsigned short*)(base + oQ);
    unsigned short* kpT = (unsigned short*)(base + oK);
    unsigned short* vpT = (unsigned short*)(base + oV);
    unsigned short* QF  = (unsigned short*)(base + oQF);
    unsigned short* KF  = (unsigned short*)(base + oKF);
    unsigned short* Rst = (unsigned short*)(base + oR);
    unsigned short* corr  = (unsigned short*)(base + oQ);    // after QF done
    float*          alphaT = (float*)(base + oQF);           // after crossspec
    unsigned short* probs = (unsigned short*)(base + oR);    // after inverse
    unsigned short* xT  = (unsigned short*)(base + oQ);      // after alphaT
    unsigned short* X   = (unsigned short*)(base + oK);      // after KF
    float*          y2  = (float*)(base + oV);               // after PV

    // tables + weight conversion
    init_tables_bf16<<<(SEQ * NFP + 255) / 256, 256, 0, stream>>>(F_stack, G_stack);
    wtrans256<<<256, 256, 0, stream>>>(w0, w0T);
    wtrans256<<<256, 256, 0, stream>>>(w1, w1T);
    wtrans256<<<256, 256, 0, stream>>>(w2, w2T);
    fconv<<<(LS * DK + 255) / 256, 256, 0, stream>>>(w3, w3b, LS * DK);
    fconv<<<(HID * HID + 255) / 256, 256, 0, stream>>>(lw, lwb, HID * HID);

    // projections (transposed): qpT[bh](d,s) = w0T (256x256) @ q^T   [B = raw query rows]
    dim3 gproj(4, 4, BH);
    mgemm<true, 0><<<gproj, 256, 0, stream>>>(w0T, query, qpT, DK, SEQ, DK, DK, HID, SEQ,
        0L, 0L, (long)SEQ * HID, (long)DK, (long)NH * DK * SEQ, (long)DK * SEQ, NH, nullptr);
    mgemm<true, 0><<<gproj, 256, 0, stream>>>(w1T, key, kpT, DK, SEQ, DK, DK, HID, SEQ,
        0L, 0L, (long)SEQ * HID, (long)DK, (long)NH * DK * SEQ, (long)DK * SEQ, NH, nullptr);
    mgemm<true, 0><<<gproj, 256, 0, stream>>>(w2T, value, vpT, DK, SEQ, DK, DK, HID, SEQ,
        0L, 0L, (long)SEQ * HID, (long)DK, (long)NH * DK * SEQ, (long)DK * SEQ, NH, nullptr);

    // forward DFT: QF[bh](d, 202) = qpT @ F_stack^T
    dim3 gfwd((NF2 + 63) / 64, 4, BH);
    mgemm<false, 0><<<gfwd, 256, 0, stream>>>(qpT, F_stack, QF, DK, NF2, SEQ, SEQ, SEQ, NFP,
        (long)DK * SEQ, 0L, 0L, 0L, (long)DK * NFP, 0L, 1, nullptr);
    mgemm<false, 0><<<gfwd, 256, 0, stream>>>(kpT, F_stack, KF, DK, NF2, SEQ, SEQ, SEQ, NFP,
        (long)DK * SEQ, 0L, 0L, 0L, (long)DK * NFP, 0L, 1, nullptr);

    // cross-spectrum * weight
    long ncs = (long)BH * DK * NF;
    crossspec<<<(unsigned)((ncs + 255) / 256), 256, 0, stream>>>(QF, KF, cw, Rst);

    // inverse DFT: corr[bh](s,d) = G_stack @ R^T, epilogue relu(+bias)
    dim3 ginv(4, (SEQ + 63) / 64, BH);
    mgemm<false, 2><<<ginv, 256, 0, stream>>>(G_stack, Rst, corr, SEQ, DK, NF2, NFP, NFP, DK,
        0L, 0L, (long)DK * NFP, 0L, (long)SEQ * DK, 0L, 1, attn_bias);

    // alphaT[bh](l,s) = w3 @ corr^T-form
    dim3 galp(4, 4, BH);
    mgemm<false, 1><<<galp, 256, 0, stream>>>(w3b, corr, alphaT, LS, SEQ, DK, DK, DK, SEQ,
        0L, 0L, (long)SEQ * DK, 0L, (long)LS * SEQ, 0L, 1, nullptr);

    // softmax over contiguous s
    softmax_rows<<<(unsigned)(BH * LS / 4), 256, 0, stream>>>(alphaT, probs);

    // xT[bh](d,l) = vpT @ probs^T-form
    dim3 gpv(4, 4, BH);
    mgemm<false, 0><<<gpv, 256, 0, stream>>>(vpT, probs, xT, DK, LS, SEQ, SEQ, SEQ, LS,
        (long)DK * SEQ, 0L, (long)LS * SEQ, 0L, (long)DK * LS, 0L, 1, nullptr);

    // transpose to X (b, l, hid)
    transposeX<<<dim3(4, 4, BH), 256, 0, stream>>>(xT, X);

    // y2 = X @ lw^T + lb  (25600 x 1024 x 1024)
    dim3 glin(HID / 64, (BATCH * LS) / 64, 1);
    mgemm<false, 3><<<glin, 256, 0, stream>>>(X, lwb, y2, BATCH * LS, HID, HID, HID, HID, HID,
        0L, 0L, 0L, 0L, 0L, 0L, 1, lb);

    // gelu + LayerNorm
    gelu_ln_kernel<<<(unsigned)(BATCH * LS), 256, 0, stream>>>(y2, lnw, lnb, out);
}

// Round 3
// 720.474 us; speedup vs baseline: 6.5422x; 1.3345x over previous
//
#include <hip/hip_runtime.h>
#include <hip/hip_bf16.h>
#include <math.h>

#define BATCH 128
#define SEQ   200
#define HID   1024
#define NH    4
#define DK    256
#define NF    101    // SEQ/2+1
#define NF2   202    // stacked real+imag rows
#define LS    200
#define PD    256    // padded s / fidx / l dimension

typedef __attribute__((ext_vector_type(8))) short bf16x8;
typedef __attribute__((ext_vector_type(4))) float f32x4;

__device__ __forceinline__ unsigned short f2bf(float f) {
    union { float f; unsigned u; } v; v.f = f;
    unsigned r = v.u + 0x7fff + ((v.u >> 16) & 1);
    return (unsigned short)(r >> 16);
}
__device__ __forceinline__ float bf2f(unsigned short h) {
    union { unsigned u; float f; } v; v.u = ((unsigned)h) << 16;
    return v.f;
}

__device__ __forceinline__ void gld_lds16(const void* g, void* l) {
    __builtin_amdgcn_global_load_lds(
        (const __attribute__((address_space(1))) unsigned*)g,
        (__attribute__((address_space(3))) unsigned*)l, 16, 0, 0);
}

// ---------------------------------------------------------------------------
// Tables, all padded to 256x256, pad = 0.
// F[fidx][s]: fidx<101: cos(2pi f s/200)/sqrt(200); 101..201: -sin; else 0
// G[s][j]:    j<101: a_j cos(..)/sqrt(200) (a=1 for j in {0,100} else 2);
//             j=101+f (f not in {0,100}): -2 sin(..)/sqrt(200); else 0
// ---------------------------------------------------------------------------
__global__ void init_tables_bf16(unsigned short* __restrict__ F, unsigned short* __restrict__ G) {
    int idx = blockIdx.x * 256 + threadIdx.x;
    const double inv = 0.07071067811865475244;
    const double PI2 = 6.283185307179586476925;
    {
        int fidx = idx >> 8, s = idx & 255;
        double v = 0.0;
        if (s < SEQ && fidx < NF2) {
            int f = (fidx < NF) ? fidx : fidx - NF;
            double ang = PI2 * (double)((f * s) % SEQ) / (double)SEQ;
            v = (fidx < NF) ? cos(ang) * inv : -sin(ang) * inv;
        }
        F[idx] = f2bf((float)v);
    }
    {
        int s = idx >> 8, j = idx & 255;
        double v = 0.0;
        if (s < SEQ && j < NF2) {
            if (j < NF) {
                double al = (j == 0 || j == NF - 1) ? 1.0 : 2.0;
                v = al * cos(PI2 * (double)((j * s) % SEQ) / (double)SEQ) * inv;
            } else {
                int f = j - NF;
                if (f != 0 && f != NF - 1)
                    v = -2.0 * sin(PI2 * (double)((f * s) % SEQ) / (double)SEQ) * inv;
            }
        }
        G[idx] = f2bf((float)v);
    }
}

__global__ void wtrans256(const float* __restrict__ src, unsigned short* __restrict__ dst) {
    int dout = blockIdx.x, din = threadIdx.x;
    dst[dout * 256 + din] = f2bf(src[din * 256 + dout]);
}

__global__ void w3pad(const float* __restrict__ src, unsigned short* __restrict__ dst) {
    int row = blockIdx.x, col = threadIdx.x;
    dst[row * 256 + col] = (row < LS) ? f2bf(src[row * 256 + col]) : (unsigned short)0;
}

__global__ void fconv(const float* __restrict__ src, unsigned short* __restrict__ dst, int n) {
    int i = blockIdx.x * 256 + threadIdx.x;
    if (i < n) dst[i] = f2bf(src[i]);
}

// ---------------------------------------------------------------------------
// m97-structure bf16 MFMA GEMM: 128x128 tile, BK=64, 4 waves (each 64x64 =
// 4x4 16x16 frags), single-buffer LDS, global_load_lds 16B staging (linear
// LDS dest = wave-uniform base + lane*16 by construction). No bounds checks:
// M,N multiples of 128, K multiple of 64, pads are zero.
// B_F32: B operand is fp32, reg-staged with convert; rows >= nbValid -> 0.
// EPI: 0 bf16; 1 f32; 2 relu(acc+biasN)->bf16; 3 acc+biasN->f32
// ---------------------------------------------------------------------------
template <bool B_F32, int EPI>
__global__ __launch_bounds__(256)
void mgemm128(const void* __restrict__ Av, const void* __restrict__ Bv, void* __restrict__ Cv,
              int K, int lda, int ldb, int ldc,
              long aOuter, long aInner, long bOuter, long bInner,
              long cOuter, long cInner, int nInner, int nbValid,
              const float* __restrict__ biasN) {
    int bz = blockIdx.z;
    int bo = bz / nInner, bi = bz - bo * nInner;
    const unsigned short* A = (const unsigned short*)Av + bo * aOuter + bi * aInner;
    const unsigned short* Bh = nullptr;
    const float* Bf = nullptr;
    if (B_F32) Bf = (const float*)Bv + bo * bOuter + bi * bInner;
    else       Bh = (const unsigned short*)Bv + bo * bOuter + bi * bInner;

    __shared__ unsigned short As[128 * 64];
    __shared__ unsigned short Bs[128 * 64];

    int t = threadIdx.x;
    int m0 = blockIdx.y * 128, n0 = blockIdx.x * 128;
    int lane = t & 63, wave = t >> 6;
    int wr = wave >> 1, wc = wave & 1;
    int la = lane & 15, hi = lane >> 4;

    f32x4 acc[4][4] = {};

    int rsub = t >> 3;          // 0..31: row within 32-row round
    int c8 = (t & 7) * 8;       // k element offset (8 bf16 = 16B)

    for (int k0 = 0; k0 < K; k0 += 64) {
#pragma unroll
        for (int p = 0; p < 4; ++p) {
            int row = p * 32 + rsub;
            gld_lds16(A + (long)(m0 + row) * lda + k0 + c8, &As[row * 64 + c8]);
        }
        if (!B_F32) {
#pragma unroll
            for (int p = 0; p < 4; ++p) {
                int row = p * 32 + rsub;
                gld_lds16(Bh + (long)(n0 + row) * ldb + k0 + c8, &Bs[row * 64 + c8]);
            }
        } else {
#pragma unroll
            for (int p = 0; p < 4; ++p) {
                int row = p * 32 + rsub;
                int gn = n0 + row;
                unsigned short tmp[8];
                if (gn < nbValid) {
                    const float4* src = reinterpret_cast<const float4*>(Bf + (long)gn * ldb + k0 + c8);
                    float4 x0 = src[0], x1 = src[1];
                    tmp[0] = f2bf(x0.x); tmp[1] = f2bf(x0.y); tmp[2] = f2bf(x0.z); tmp[3] = f2bf(x0.w);
                    tmp[4] = f2bf(x1.x); tmp[5] = f2bf(x1.y); tmp[6] = f2bf(x1.z); tmp[7] = f2bf(x1.w);
                } else {
#pragma unroll
                    for (int j = 0; j < 8; ++j) tmp[j] = 0;
                }
                *(bf16x8*)&Bs[row * 64 + c8] = *(bf16x8*)tmp;
            }
        }
        __syncthreads();
#pragma unroll
        for (int half = 0; half < 2; ++half) {
            int ko = half * 32 + hi * 8;
            bf16x8 a[4], b[4];
#pragma unroll
            for (int mi = 0; mi < 4; ++mi)
                a[mi] = *(const bf16x8*)&As[(wr * 64 + mi * 16 + la) * 64 + ko];
#pragma unroll
            for (int ni = 0; ni < 4; ++ni)
                b[ni] = *(const bf16x8*)&Bs[(wc * 64 + ni * 16 + la) * 64 + ko];
#pragma unroll
            for (int mi = 0; mi < 4; ++mi)
#pragma unroll
                for (int ni = 0; ni < 4; ++ni)
                    acc[mi][ni] = __builtin_amdgcn_mfma_f32_16x16x32_bf16(a[mi], b[ni], acc[mi][ni], 0, 0, 0);
        }
        __syncthreads();
    }

    unsigned short* Ch = nullptr; float* Cf = nullptr;
    if (EPI == 1 || EPI == 3) Cf = (float*)Cv + bo * cOuter + bi * cInner;
    else                      Ch = (unsigned short*)Cv + bo * cOuter + bi * cInner;

#pragma unroll
    for (int mi = 0; mi < 4; ++mi) {
#pragma unroll
        for (int ni = 0; ni < 4; ++ni) {
            int gn = n0 + wc * 64 + ni * 16 + la;
            int gmB = m0 + wr * 64 + mi * 16 + hi * 4;
            float bN = 0.f;
            if (EPI == 2 || EPI == 3) bN = biasN[gn];
#pragma unroll
            for (int rr = 0; rr < 4; ++rr) {
                float v = acc[mi][ni][rr];
                long idx = (long)(gmB + rr) * ldc + gn;
                if (EPI == 0) Ch[idx] = f2bf(v);
                else if (EPI == 1) Cf[idx] = v;
                else if (EPI == 2) Ch[idx] = f2bf(fmaxf(v + bN, 0.f));
                else Cf[idx] = v + bN;
            }
        }
    }
}

// ---------------------------------------------------------------------------
// cross-spectrum * complex weight, IN PLACE on QF. Layout (bh, d, 256):
// col f<101 real, col 101+f imag, cols 202..255 zeroed.
// ---------------------------------------------------------------------------
__global__ void crossspec(unsigned short* __restrict__ QF, const unsigned short* __restrict__ KF,
                          const float* __restrict__ cw) {
    long idx = (long)blockIdx.x * 256 + threadIdx.x;
    if (idx >= (long)BATCH * NH * DK * NF) return;
    int f = (int)(idx % NF);
    long tq = idx / NF;
    int d = (int)(tq % DK);
    int bh = (int)(tq / DK);
    int h = bh & (NH - 1);
    long base = (long)bh * DK * PD + (long)d * PD;
    float qr = bf2f(QF[base + f]), qi = bf2f(QF[base + NF + f]);
    float kr = bf2f(KF[base + f]), ki = bf2f(KF[base + NF + f]);
    float cr = qr * kr + qi * ki;
    float ci = qi * kr - qr * ki;
    long wb = (((long)h * NF + f) * DK + d) * 2;
    float wr = cw[wb], wi = cw[wb + 1];
    QF[base + f]      = f2bf(cr * wr - ci * wi);
    QF[base + NF + f] = f2bf(cr * wi + ci * wr);
    if (f < PD - NF2) QF[base + NF2 + f] = 0;
}

// ---------------------------------------------------------------------------
// softmax over contiguous s (cols 0..199 of 256) per row; pad cols -> 0
// ---------------------------------------------------------------------------
__global__ __launch_bounds__(256) void softmax_rows(const float* __restrict__ in,
                                                    unsigned short* __restrict__ out) {
    long row = (long)blockIdx.x * 4 + (threadIdx.x >> 6);
    int lane = threadIdx.x & 63;
    const float* p = in + row * PD;
    float v[4];
    float m = -1e30f;
#pragma unroll
    for (int i = 0; i < 4; ++i) {
        int s = lane + 64 * i;
        v[i] = (s < SEQ) ? p[s] : -1e30f;
        m = fmaxf(m, v[i]);
    }
#pragma unroll
    for (int o = 32; o; o >>= 1) m = fmaxf(m, __shfl_xor(m, o));
    float e[4], sum = 0.f;
#pragma unroll
    for (int i = 0; i < 4; ++i) {
        int s = lane + 64 * i;
        e[i] = (s < SEQ) ? expf(v[i] - m) : 0.f;
        sum += e[i];
    }
#pragma unroll
    for (int o = 32; o; o >>= 1) sum += __shfl_xor(sum, o);
    float inv = 1.f / sum;
    unsigned short* q = out + row * PD;
#pragma unroll
    for (int i = 0; i < 4; ++i) {
        int s = lane + 64 * i;
        q[s] = (s < SEQ) ? f2bf(e[i] * inv) : (unsigned short)0;
    }
}

// ---------------------------------------------------------------------------
// xT (bh, 256 d, 256 l) bf16 -> X (b, l<200, h*256+d) bf16
// ---------------------------------------------------------------------------
__global__ __launch_bounds__(256) void transposeX(const unsigned short* __restrict__ xT,
                                                  unsigned short* __restrict__ X) {
    __shared__ unsigned short T[64][72];
    int bh = blockIdx.z, d0 = blockIdx.y * 64, l0 = blockIdx.x * 64;
    int b = bh >> 2, h = bh & 3;
    int t = threadIdx.x;
    int r = t >> 2, seg = (t & 3) * 16;
    const unsigned short* src = xT + (long)bh * PD * PD + (long)(d0 + r) * PD + l0 + seg;
    *(bf16x8*)&T[r][seg]     = *(const bf16x8*)(src);
    *(bf16x8*)&T[r][seg + 8] = *(const bf16x8*)(src + 8);
    __syncthreads();
    int l = l0 + r;
    if (l < LS) {
        unsigned short* dst = X + ((long)b * LS + l) * HID + h * DK + d0 + seg;
#pragma unroll
        for (int j = 0; j < 16; ++j) dst[j] = T[seg + j][r];
    }
}

// ---------------------------------------------------------------------------
// gelu(erf) + TF LayerNorm per 1024-wide row (fp32 in, fp32 out)
// ---------------------------------------------------------------------------
__global__ __launch_bounds__(256) void gelu_ln_kernel(const float* __restrict__ y2,
                               const float* __restrict__ lnw, const float* __restrict__ lnb,
                               float* __restrict__ out) {
    long row = blockIdx.x;
    const float4* xr = reinterpret_cast<const float4*>(y2 + row * HID);
    int tid = threadIdx.x;
    float4 v4 = xr[tid];
    float g[4];
    g[0] = 0.5f * v4.x * (1.f + erff(v4.x * 0.70710678118654752f));
    g[1] = 0.5f * v4.y * (1.f + erff(v4.y * 0.70710678118654752f));
    g[2] = 0.5f * v4.z * (1.f + erff(v4.z * 0.70710678118654752f));
    g[3] = 0.5f * v4.w * (1.f + erff(v4.w * 0.70710678118654752f));

    __shared__ float red[4];
    float s = g[0] + g[1] + g[2] + g[3];
#pragma unroll
    for (int o = 32; o > 0; o >>= 1) s += __shfl_down(s, o);
    if ((tid & 63) == 0) red[tid >> 6] = s;
    __syncthreads();
    float mean = (red[0] + red[1] + red[2] + red[3]) * (1.f / (float)HID);

    float v2 = 0.f;
#pragma unroll
    for (int p = 0; p < 4; ++p) { float d = g[p] - mean; v2 += d * d; }
    __syncthreads();
#pragma unroll
    for (int o = 32; o > 0; o >>= 1) v2 += __shfl_down(v2, o);
    if ((tid & 63) == 0) red[tid >> 6] = v2;
    __syncthreads();
    float var = (red[0] + red[1] + red[2] + red[3]) * (1.f / (float)HID);
    float rstd = rsqrtf(var + 1e-12f);

    float4 o4;
    int i0 = tid * 4;
    o4.x = (g[0] - mean) * rstd * lnw[i0 + 0] + lnb[i0 + 0];
    o4.y = (g[1] - mean) * rstd * lnw[i0 + 1] + lnb[i0 + 1];
    o4.z = (g[2] - mean) * rstd * lnw[i0 + 2] + lnb[i0 + 2];
    o4.w = (g[3] - mean) * rstd * lnw[i0 + 3] + lnb[i0 + 3];
    reinterpret_cast<float4*>(out + row * HID)[tid] = o4;
}

// ---------------------------------------------------------------------------
extern "C" void kernel_launch(void* const* d_in, const int* in_sizes, int n_in,
                              void* d_out, int out_size, void* d_ws, size_t ws_size,
                              hipStream_t stream) {
    const float* query = (const float*)d_in[0];
    const float* key   = (const float*)d_in[1];
    const float* value = (const float*)d_in[2];
    const float* w0 = (const float*)d_in[3];
    const float* w1 = (const float*)d_in[4];
    const float* w2 = (const float*)d_in[5];
    const float* w3 = (const float*)d_in[6];
    const float* attn_bias = (const float*)d_in[7];
    const float* cw = (const float*)d_in[8];
    const float* lw = (const float*)d_in[9];
    const float* lb = (const float*)d_in[10];
    const float* lnw = (const float*)d_in[11];
    const float* lnb = (const float*)d_in[12];
    float* out = (float*)d_out;

    char* base = (char*)d_ws;
    const long BH = (long)BATCH * NH;
    const long SZR = (long)BH * PD * PD;          // elements per 64MiB bf16 region
    const size_t M64 = 67108864;

    unsigned short* F_stack = (unsigned short*)(base + 0);
    unsigned short* G_stack = (unsigned short*)(base + 131072);
    unsigned short* w0T = (unsigned short*)(base + 262144);
    unsigned short* w1T = (unsigned short*)(base + 393216);
    unsigned short* w2T = (unsigned short*)(base + 524288);
    unsigned short* w3b = (unsigned short*)(base + 655360);
    unsigned short* lwb = (unsigned short*)(base + 786432);   // 2MiB
    char* rA = base + 4194304;            // qpT -> corr -> X
    char* rB = rA + M64;                  // kpT -> probs
    char* rC = rB + M64;                  // vpT
    char* rD = rC + M64;                  // QF/R -> alphaT(lo) -> y2
    char* rE = rD + M64;                  // KF   -> alphaT(hi) -> xT

    unsigned short* qpT = (unsigned short*)rA;
    unsigned short* kpT = (unsigned short*)rB;
    unsigned short* vpT = (unsigned short*)rC;
    unsigned short* QF  = (unsigned short*)rD;
    unsigned short* KF  = (unsigned short*)rE;
    unsigned short* corr = (unsigned short*)rA;
    float*          alphaT = (float*)rD;          // spans rD+rE (128 MiB)
    unsigned short* probs = (unsigned short*)rB;
    unsigned short* xT = (unsigned short*)rE;
    unsigned short* X  = (unsigned short*)rA;
    float*          y2 = (float*)rD;              // 100 MiB, after xT consumed

    // tables + weight conversion
    init_tables_bf16<<<256, 256, 0, stream>>>(F_stack, G_stack);
    wtrans256<<<256, 256, 0, stream>>>(w0, w0T);
    wtrans256<<<256, 256, 0, stream>>>(w1, w1T);
    wtrans256<<<256, 256, 0, stream>>>(w2, w2T);
    w3pad<<<256, 256, 0, stream>>>(w3, w3b);
    fconv<<<(HID * HID + 255) / 256, 256, 0, stream>>>(lw, lwb, HID * HID);

    // projections: qpT[bh](d,s) = w0T @ q^T ; B = raw fp32 rows (s<200 valid)
    dim3 gproj(2, 2, BH);
    mgemm128<true, 0><<<gproj, 256, 0, stream>>>(w0T, query, qpT, DK, DK, HID, PD,
        0L, 0L, (long)SEQ * HID, (long)DK, (long)NH * PD * PD, (long)PD * PD, NH, SEQ, nullptr);
    mgemm128<true, 0><<<gproj, 256, 0, stream>>>(w1T, key, kpT, DK, DK, HID, PD,
        0L, 0L, (long)SEQ * HID, (long)DK, (long)NH * PD * PD, (long)PD * PD, NH, SEQ, nullptr);
    mgemm128<true, 0><<<gproj, 256, 0, stream>>>(w2T, value, vpT, DK, DK, HID, PD,
        0L, 0L, (long)SEQ * HID, (long)DK, (long)NH * PD * PD, (long)PD * PD, NH, SEQ, nullptr);

    // forward DFT (q and k batched via bo): QF[bh](d,f) = qpT @ F^T
    dim3 gfwd(2, 2, 2 * BH);
    mgemm128<false, 0><<<gfwd, 256, 0, stream>>>(qpT, F_stack, QF, PD, PD, PD, PD,
        SZR, (long)PD * PD, 0L, 0L, SZR, (long)PD * PD, (int)BH, PD, nullptr);

    // cross-spectrum * weight (in place on QF)
    long ncs = (long)BH * DK * NF;
    crossspec<<<(unsigned)((ncs + 255) / 256), 256, 0, stream>>>(QF, KF, cw);

    // inverse DFT: corr[bh](s,d) = G @ R^T, epilogue relu(+attn_bias over d)
    dim3 gstd(2, 2, BH);
    mgemm128<false, 2><<<gstd, 256, 0, stream>>>(G_stack, QF, corr, PD, PD, PD, PD,
        0L, 0L, (long)PD * PD, 0L, (long)PD * PD, 0L, 1, PD, attn_bias);

    // alphaT[bh](l,s) = w3b @ corr^T-form (f32 out for softmax)
    mgemm128<false, 1><<<gstd, 256, 0, stream>>>(w3b, corr, alphaT, PD, PD, PD, PD,
        0L, 0L, (long)PD * PD, 0L, (long)PD * PD, 0L, 1, PD, nullptr);

    // softmax over contiguous s
    softmax_rows<<<(unsigned)(BH * PD / 4), 256, 0, stream>>>(alphaT, probs);

    // xT[bh](d,l) = vpT @ probs^T-form
    mgemm128<false, 0><<<gstd, 256, 0, stream>>>(vpT, probs, xT, PD, PD, PD, PD,
        (long)PD * PD, 0L, (long)PD * PD, 0L, (long)PD * PD, 0L, 1, PD, nullptr);

    // transpose to X (b, l, hid)
    transposeX<<<dim3(4, 4, BH), 256, 0, stream>>>(xT, X);

    // y2 = X @ lw^T + lb : 25600 x 1024 x 1024
    dim3 glin(HID / 128, (BATCH * LS) / 128, 1);
    mgemm128<false, 3><<<glin, 256, 0, stream>>>(X, lwb, y2, HID, HID, HID, HID,
        0L, 0L, 0L, 0L, 0L, 0L, 1, HID, lb);

    // gelu + LayerNorm
    gelu_ln_kernel<<<(unsigned)(BATCH * LS), 256, 0, stream>>>(y2, lnw, lnb, out);
}